// Round 1
// baseline (452.144 us; speedup 1.0000x reference)
//
#include <hip/hip_runtime.h>

// y[m, p*32+q] = sum_{r,s} x[m, r*32+s] * W2[p,r] * W1[q,s] + bias[p*32+q]
//   == (W2 · X_m · W1^T)[p,q],  X_m = reshape(x[m], 32, 32)
//
// One wave per row m. Stage 1: T = X·W1^T (2x mfma_32x32x16_bf16).
// Stage 2 computes the TRANSPOSED product C[q][p] = sum_r T[r][q]·W2[p][r]
// with the T-fragment as the A operand, built entirely in-register from the
// stage-1 accumulator via v_cvt_pk_bf16_f32 + permlane32_swap (no LDS).
// Bias is preloaded into the stage-2 accumulator (C operand), epilogue is
// 4x global_store_dwordx4 per lane. 1-row software prefetch of x.

typedef short bf16x8 __attribute__((ext_vector_type(8)));   // 8 bf16 = 4 VGPRs
typedef float f32x16 __attribute__((ext_vector_type(16)));  // C/D acc
typedef unsigned uint32x2 __attribute__((ext_vector_type(2)));
typedef unsigned uint32x4 __attribute__((ext_vector_type(4)));

#define MFMA32(A, B, C) __builtin_amdgcn_mfma_f32_32x32x16_bf16((A), (B), (C), 0, 0, 0)

// two f32 -> one dword of two bf16 (RNE), low = lo, high = hi
__device__ __forceinline__ unsigned pk2(float lo, float hi) {
    unsigned r;
    asm("v_cvt_pk_bf16_f32 %0, %1, %2" : "=v"(r) : "v"(lo), "v"(hi));
    return r;
}

// fp32 -> bf16 RNE (loop-invariant weight fragments only)
__device__ __forceinline__ short f2bf(float f) {
    unsigned u = __builtin_bit_cast(unsigned, f);
    u = (u + 0x7fffu + ((u >> 16) & 1u)) >> 16;
    return (short)u;
}

constexpr int M_TOTAL = 8 * 8192;   // 65536 rows of 1024
constexpr int BLOCKS  = 2048;
constexpr int TPB     = 256;        // 4 waves/block
constexpr int NWAVES  = BLOCKS * (TPB / 64);   // 8192 waves
constexpr int RPW     = M_TOTAL / NWAVES;      // 8 rows/wave

__global__ __launch_bounds__(TPB) void kron_mlp_kernel(
    const float* __restrict__ x,    // (65536, 1024)
    const float* __restrict__ w1,   // (32, 32): W1[q][s]
    const float* __restrict__ w2,   // (32, 32): W2[p][r]
    const float* __restrict__ bias, // (1024,)
    float* __restrict__ out)        // (65536, 1024)
{
    const int tid  = threadIdx.x;
    const int wid  = tid >> 6;
    const int lane = tid & 63;
    const int c    = lane & 31;   // stage1: A row r / B col q.  stage2: B col p.
    const int h    = lane >> 5;   // half-wave k-range selector

    // ---- loop-invariant fragments ----
    // Stage-1 B (W1^T): element[k=8h+j][n=c] = W1[c][8h+j]   (b1: +16)
    // Stage-2 B (W2^T as B[r][p]=W2[p][r]): element[k=8h+j][n=c] = W2[c][8h+j]
    bf16x8 w1b0, w1b1, w2b0, w2b1;
    {
        const float* p1 = w1 + c * 32 + 8 * h;
        const float* p2 = w2 + c * 32 + 8 * h;
        #pragma unroll
        for (int j = 0; j < 8; ++j) {
            w1b0[j] = f2bf(p1[j]);  w1b1[j] = f2bf(p1[16 + j]);
            w2b0[j] = f2bf(p2[j]);  w2b1[j] = f2bf(p2[16 + j]);
        }
    }

    // Stage-2 C-init = bias. C/D: col=p=c, row=q=(reg&3)+8*(reg>>2)+4h,
    // y-index = p*32+q -> reg 4g+i corresponds to bias[c*32 + 8g + 4h + i].
    f32x16 yinit;
    #pragma unroll
    for (int g = 0; g < 4; ++g) {
        const float4 b4 = *(const float4*)(bias + c * 32 + 8 * g + 4 * h);
        yinit[4 * g + 0] = b4.x; yinit[4 * g + 1] = b4.y;
        yinit[4 * g + 2] = b4.z; yinit[4 * g + 3] = b4.w;
    }

    const int gwave = blockIdx.x * (TPB / 64) + wid;
    const size_t STRIDE = (size_t)NWAVES * 1024;

    const float* xp = x   + (size_t)gwave * 1024 + c * 32 + 8 * h;
    float*       op = out + (size_t)gwave * 1024 + c * 32 + 4 * h;

    auto run_row = [&](const float4& xa, const float4& xb,
                       const float4& xc, const float4& xd, float* o) {
        // Stage-1 A (X_m): element[row=c][k=8h+j] = x[c*32 + 8h + j] (a1: +16)
        uint32x4 ua = { pk2(xa.x, xa.y), pk2(xa.z, xa.w),
                        pk2(xb.x, xb.y), pk2(xb.z, xb.w) };
        uint32x4 ub = { pk2(xc.x, xc.y), pk2(xc.z, xc.w),
                        pk2(xd.x, xd.y), pk2(xd.z, xd.w) };

        // Stage 1: T = X · W1^T  (K=32 as two K=16 MFMAs)
        f32x16 t = {};
        t = MFMA32(__builtin_bit_cast(bf16x8, ua), w1b0, t);
        t = MFMA32(__builtin_bit_cast(bf16x8, ub), w1b1, t);

        // In-register re-layout: lane (c,h') reg r holds T[(r&3)+8*(r>>2)+4h'][c].
        // Stage-2 A fragment needs element[row=c][k]: tb0[j]=T[8h+j][c],
        // tb1[j]=T[16+8h+j][c]. Pack pairs to bf16 dwords, then one
        // permlane32_swap fills two operand words:
        //   swap(A,B): new_A = {A.lo31, B.lo31}, new_B = {A.hi31, B.hi31}
        uint32x2 r0 = __builtin_amdgcn_permlane32_swap(pk2(t[0],  t[1]),  pk2(t[4],  t[5]),  false, false);
        uint32x2 r1 = __builtin_amdgcn_permlane32_swap(pk2(t[2],  t[3]),  pk2(t[6],  t[7]),  false, false);
        uint32x2 r2 = __builtin_amdgcn_permlane32_swap(pk2(t[8],  t[9]),  pk2(t[12], t[13]), false, false);
        uint32x2 r3 = __builtin_amdgcn_permlane32_swap(pk2(t[10], t[11]), pk2(t[14], t[15]), false, false);
        uint32x4 utb0 = { r0[0], r1[0], r0[1], r1[1] };
        uint32x4 utb1 = { r2[0], r3[0], r2[1], r3[1] };

        // Stage 2 (transposed): C[q][p] = sum_r T[r][q] * W2[p][r], C init = bias
        f32x16 yv = yinit;
        yv = MFMA32(__builtin_bit_cast(bf16x8, utb0), w2b0, yv);
        yv = MFMA32(__builtin_bit_cast(bf16x8, utb1), w2b1, yv);

        // Epilogue: reg 4g+i -> out[c*32 + 8g + 4h + i]: 4 dwordx4 stores
        #pragma unroll
        for (int g = 0; g < 4; ++g) {
            float4 ov = { yv[4 * g + 0], yv[4 * g + 1],
                          yv[4 * g + 2], yv[4 * g + 3] };
            *(float4*)(o + g * 8) = ov;
        }
    };

    // x-row fragment loads: 4x float4 per lane at c*128B + h*32B (+0,+16,+64,+80)
    float4 xa = *(const float4*)(xp + 0);
    float4 xb = *(const float4*)(xp + 4);
    float4 xc = *(const float4*)(xp + 16);
    float4 xd = *(const float4*)(xp + 20);

    #pragma unroll 1
    for (int it = 0; it < RPW - 1; ++it) {
        const float* np = xp + STRIDE;          // prefetch next row first
        float4 na = *(const float4*)(np + 0);
        float4 nb = *(const float4*)(np + 4);
        float4 nc = *(const float4*)(np + 16);
        float4 nd = *(const float4*)(np + 20);
        run_row(xa, xb, xc, xd, op);
        xa = na; xb = nb; xc = nc; xd = nd;
        xp = np; op += STRIDE;
    }
    run_row(xa, xb, xc, xd, op);
}

extern "C" void kernel_launch(void* const* d_in, const int* in_sizes, int n_in,
                              void* d_out, int out_size, void* d_ws, size_t ws_size,
                              hipStream_t stream) {
    const float* x    = (const float*)d_in[0];
    const float* w1   = (const float*)d_in[1];
    const float* w2   = (const float*)d_in[2];
    const float* bias = (const float*)d_in[3];
    float* out        = (float*)d_out;
    kron_mlp_kernel<<<dim3(BLOCKS), dim3(TPB), 0, stream>>>(x, w1, w2, bias, out);
}